// Round 16
// baseline (423.883 us; speedup 1.0000x reference)
//
#include <hip/hip_runtime.h>
#include <hip/hip_bf16.h>

typedef unsigned short ushort_t;
typedef short s8v __attribute__((ext_vector_type(8)));      // 8 bf16 bit-patterns
typedef ushort_t u16x8 __attribute__((ext_vector_type(8))); // 8 ushorts (16B)
typedef float f32x4 __attribute__((ext_vector_type(4)));

// Problem constants
constexpr int B_ = 2;
constexpr int C_ = 256;
constexpr int S_TOT = 48 * 48;   // 2304
constexpr int HEADS_ = 8;
constexpr int JSPLIT = 12;       // scores j-chunks (Z partials)
#define INV_SQRT_DH 0.17677669529663688f

__device__ __forceinline__ ushort_t bf16_rn(float x) {
  unsigned u = __float_as_uint(x);
  return (ushort_t)((u + 0x7fffu + ((u >> 16) & 1u)) >> 16);
}

// ---------------------------------------------------------------------------
// Kernel 1 (fused both MLP layers x3 tensors + conv-weight repack plane):
// z=0: Q [b][s][C]; z=1: K [b][s][C]; z=2: V^T [b][C][s];
// z=3: repack+split conv weights (b selects conv1/conv2).
// grid (72, B, 4), block 256.
// ---------------------------------------------------------------------------
__global__ __launch_bounds__(256) void k_mlpf(
    const float* __restrict__ x, const float* __restrict__ ref,
    const float* __restrict__ qW1, const float* __restrict__ qb1,
    const float* __restrict__ qW2, const float* __restrict__ qb2,
    const float* __restrict__ kW1, const float* __restrict__ kb1,
    const float* __restrict__ kW2, const float* __restrict__ kb2,
    const float* __restrict__ vW1, const float* __restrict__ vb1,
    const float* __restrict__ vW2, const float* __restrict__ vb2,
    const float* __restrict__ c1W, const float* __restrict__ c2W,
    ushort_t* __restrict__ Qh, ushort_t* __restrict__ Ql,
    ushort_t* __restrict__ Kh, ushort_t* __restrict__ Kl,
    ushort_t* __restrict__ VhT, ushort_t* __restrict__ VlT,
    ushort_t* __restrict__ Wh1, ushort_t* __restrict__ Wl1,
    ushort_t* __restrict__ Wh2, ushort_t* __restrict__ Wl2) {
  __shared__ __align__(16) float in_s[32][260];
  __shared__ __align__(16) float h_s[32][260];
  const int tid = threadIdx.x;
  const int b  = blockIdx.y;
  const int z  = blockIdx.z;

  if (z == 3) {
    // repack: 2304 (co,tap) pairs over 72 blocks -> 32 pairs/block, ci=tid
    const float* W = b ? c2W : c1W;
    ushort_t* Wh = b ? Wh2 : Wh1;
    ushort_t* Wl = b ? Wl2 : Wl1;
    const int ci = tid;
#pragma unroll 4
    for (int k = 0; k < 32; ++k) {
      int p = blockIdx.x * 32 + k;
      int co = p / 9, tap = p - co * 9;
      float v = W[((size_t)co * 256 + ci) * 9 + tap];
      ushort_t h = bf16_rn(v);
      float r = __uint_as_float((unsigned)h << 16);
      ushort_t l = bf16_rn(v - r);
      size_t o = ((size_t)tap * 256 + co) * 256 + ci;
      Wh[o] = h;
      Wl[o] = l;
    }
    return;
  }

  const int s0 = blockIdx.x * 32;
  const float* in = (z == 0) ? x : ref;
  const float* W1 = (z == 0) ? qW1 : (z == 1) ? kW1 : vW1;
  const float* b1 = (z == 0) ? qb1 : (z == 1) ? kb1 : vb1;
  const float* W2 = (z == 0) ? qW2 : (z == 1) ? kW2 : vW2;
  const float* b2 = (z == 0) ? qb2 : (z == 1) ? kb2 : vb2;

  for (int idx = tid; idx < 32 * 256; idx += 256) {
    int ci = idx >> 5, r = idx & 31;
    in_s[r][ci] = in[((size_t)b * C_ + ci) * S_TOT + s0 + r];
  }
  __syncthreads();

  const int co = tid;
  float acc[32];
#pragma unroll
  for (int r = 0; r < 32; ++r) acc[r] = 0.f;
  for (int c4 = 0; c4 < 64; ++c4) {
    const float w0 = W1[(c4 * 4 + 0) * C_ + co];
    const float w1 = W1[(c4 * 4 + 1) * C_ + co];
    const float w2 = W1[(c4 * 4 + 2) * C_ + co];
    const float w3 = W1[(c4 * 4 + 3) * C_ + co];
#pragma unroll
    for (int r = 0; r < 32; ++r) {
      float4 a = *(const float4*)&in_s[r][c4 * 4];
      acc[r] = fmaf(a.x, w0, fmaf(a.y, w1, fmaf(a.z, w2, fmaf(a.w, w3, acc[r]))));
    }
  }
  {
    const float bi = b1[co];
#pragma unroll
    for (int r = 0; r < 32; ++r) h_s[r][co] = fmaxf(acc[r] + bi, 0.f);
  }
  __syncthreads();

#pragma unroll
  for (int r = 0; r < 32; ++r) acc[r] = 0.f;
  for (int c4 = 0; c4 < 64; ++c4) {
    const float w0 = W2[(c4 * 4 + 0) * C_ + co];
    const float w1 = W2[(c4 * 4 + 1) * C_ + co];
    const float w2 = W2[(c4 * 4 + 2) * C_ + co];
    const float w3 = W2[(c4 * 4 + 3) * C_ + co];
#pragma unroll
    for (int r = 0; r < 32; ++r) {
      float4 a = *(const float4*)&h_s[r][c4 * 4];
      acc[r] = fmaf(a.x, w0, fmaf(a.y, w1, fmaf(a.z, w2, fmaf(a.w, w3, acc[r]))));
    }
  }
  const float bi = b2[co];

  if (z < 2) {
    ushort_t* Ph = (z == 0) ? Qh : Kh;
    ushort_t* Pl = (z == 0) ? Ql : Kl;
#pragma unroll 4
    for (int r = 0; r < 32; ++r) {
      float y = fmaxf(acc[r] + bi, 0.f);
      ushort_t h = bf16_rn(y);
      float hf = __uint_as_float((unsigned)h << 16);
      ushort_t l = bf16_rn(y - hf);
      size_t o = ((size_t)b * S_TOT + s0 + r) * C_ + co;
      Ph[o] = h;
      Pl[o] = l;
    }
  } else {
    ushort_t hs[32], ls[32];
#pragma unroll
    for (int r = 0; r < 32; ++r) {
      float y = fmaxf(acc[r] + bi, 0.f);
      ushort_t h = bf16_rn(y);
      float hf = __uint_as_float((unsigned)h << 16);
      hs[r] = h;
      ls[r] = bf16_rn(y - hf);
    }
    size_t base = ((size_t)b * C_ + co) * S_TOT + s0;
#pragma unroll
    for (int k = 0; k < 4; ++k) {
      u16x8 hv, lv;
#pragma unroll
      for (int q = 0; q < 8; ++q) { hv[q] = hs[k * 8 + q]; lv[q] = ls[k * 8 + q]; }
      *(u16x8*)(VhT + base + k * 8) = hv;
      *(u16x8*)(VlT + base + k * 8) = lv;
    }
  }
}

// ---------------------------------------------------------------------------
// Kernel 2 (MFMA): scores + top-1-over-heads mask -> U bf16 + Z partials.
// grid (36, JSPLIT=12, B) = 864 blocks; K in 3 tiles of 64 rows (64 KiB);
// natural VGPR (no cap — round-3/12 spill lesson). U stores batched via
// 16 KB LDS buffer (round-14 win). LDS total 80 KiB -> 2 blocks/CU.
// ---------------------------------------------------------------------------
__global__ __launch_bounds__(256) void k_scores_mfma(
    const ushort_t* __restrict__ Qh, const ushort_t* __restrict__ Ql,
    const ushort_t* __restrict__ Kh, const ushort_t* __restrict__ Kl,
    ushort_t* __restrict__ U, float* __restrict__ st_z) {
  __shared__ __align__(16) uint4 kh_s[64 * 32];        // 32 KB
  __shared__ __align__(16) uint4 kl_s[64 * 32];        // 32 KB
  __shared__ __align__(16) ushort_t u_ls[8 * 64 * 16]; // 16 KB (one jsub tile)
  const int tid = threadIdx.x;
  const int w = tid >> 6, lane = tid & 63;
  const int li = lane & 15, kg = lane >> 4;
  const int i0 = blockIdx.x * 64;
  const int js = blockIdx.y;          // 0..11
  const int b  = blockIdx.z;
  const int jbase = js * 192;         // 3 j-tiles of 64 per chunk

  s8v ahi[8], alo[8];
  {
    const ushort_t* qh = Qh + ((size_t)b * S_TOT + i0 + w * 16 + li) * C_ + kg * 8;
    const ushort_t* ql = Ql + ((size_t)b * S_TOT + i0 + w * 16 + li) * C_ + kg * 8;
#pragma unroll
    for (int h = 0; h < 8; ++h) {
      ahi[h] = __builtin_bit_cast(s8v, *(const uint4*)(qh + h * 32));
      alo[h] = __builtin_bit_cast(s8v, *(const uint4*)(ql + h * 32));
    }
  }

  float zacc[4][8];
#pragma unroll
  for (int r = 0; r < 4; ++r)
#pragma unroll
    for (int h = 0; h < 8; ++h) zacc[r][h] = 0.f;

  for (int jt = 0; jt < 3; ++jt) {
    const int j0 = jbase + jt * 64;
    for (int e = tid; e < 2048; e += 256) {
      int r = e >> 5, c = e & 31;
      size_t goff = ((size_t)b * S_TOT + j0 + r) * C_ + c * 8;
      int cs = c ^ (r & 7);
      kh_s[r * 32 + cs] = *(const uint4*)(Kh + goff);
      kl_s[r * 32 + cs] = *(const uint4*)(Kl + goff);
    }
    __syncthreads();

#pragma unroll
    for (int jsub = 0; jsub < 4; ++jsub) {
      const int rj = jsub * 16 + li;
      f32x4 sc[8];
#pragma unroll
      for (int h = 0; h < 8; ++h) {
        const int cs = (h * 4 + kg) ^ (rj & 7);
        s8v bhi = __builtin_bit_cast(s8v, kh_s[rj * 32 + cs]);
        s8v blo = __builtin_bit_cast(s8v, kl_s[rj * 32 + cs]);
        f32x4 acc = {0.f, 0.f, 0.f, 0.f};
        acc = __builtin_amdgcn_mfma_f32_16x16x32_bf16(ahi[h], bhi, acc, 0, 0, 0);
        acc = __builtin_amdgcn_mfma_f32_16x16x32_bf16(ahi[h], blo, acc, 0, 0, 0);
        acc = __builtin_amdgcn_mfma_f32_16x16x32_bf16(alo[h], bhi, acc, 0, 0, 0);
        sc[h] = acc;
      }
#pragma unroll
      for (int reg = 0; reg < 4; ++reg) {
        float s8_[8];
        float thr = -1e30f;
#pragma unroll
        for (int h = 0; h < 8; ++h) {
          s8_[h] = sc[h][reg] * INV_SQRT_DH;
          thr = fmaxf(thr, s8_[h]);
        }
        const int il = w * 16 + kg * 4 + reg;
#pragma unroll
        for (int h = 0; h < 8; ++h) {
          float mv = s8_[h] < thr ? -1e18f : s8_[h];
          float uf = __expf(mv);            // 0 exactly when masked
          ushort_t ub = bf16_rn(uf);
          u_ls[(h * 64 + il) * 16 + li] = ub;
          zacc[reg][h] += __uint_as_float((unsigned)ub << 16);
        }
      }
      __syncthreads();   // u_ls writes visible
#pragma unroll
      for (int k = 0; k < 4; ++k) {
        int c = tid + k * 256;
        int h = c >> 7, ii = (c >> 1) & 63, jh = c & 1;
        u16x8 v = *(const u16x8*)&u_ls[(h * 64 + ii) * 16 + jh * 8];
        *(u16x8*)(U + ((size_t)((b * 8 + h) * S_TOT + i0 + ii)) * S_TOT
                    + j0 + jsub * 16 + jh * 8) = v;
      }
      __syncthreads();   // u_ls reads done before next jsub overwrites
    }
  }

#pragma unroll
  for (int reg = 0; reg < 4; ++reg) {
#pragma unroll
    for (int h = 0; h < 8; ++h) {
      float z = zacc[reg][h];
      z += __shfl_xor(z, 1);
      z += __shfl_xor(z, 2);
      z += __shfl_xor(z, 4);
      z += __shfl_xor(z, 8);
      if (li == 0) {
        const int i = i0 + w * 16 + kg * 4 + reg;
        size_t sidx = ((size_t)(js * B_ + b) * HEADS_ + h) * S_TOT + i;
        st_z[sidx] = z;
      }
    }
  }
}

// ---------------------------------------------------------------------------
// Kernel 3: probs = U/Z + partial ctx via bf16 MFMA, j-split 3-way.
// grid (36 i-tiles, 8 h, 6 = jc*2+b) = 1728 blocks, block 256.
// U read via NONTEMPORAL loads (read-once); probs + ctx partials nt-stored.
// ---------------------------------------------------------------------------
__global__ __launch_bounds__(256) void k_pv5(const ushort_t* __restrict__ U,
                                             const float* __restrict__ st_z,
                                             const ushort_t* __restrict__ VhT,
                                             const ushort_t* __restrict__ VlT,
                                             float* __restrict__ probs,
                                             float* __restrict__ part0,
                                             float* __restrict__ part1,
                                             float* __restrict__ part2) {
  __shared__ __align__(16) ushort_t u_s[2][64 * 64];
  __shared__ __align__(16) ushort_t vh_s[2][32 * 64];
  __shared__ __align__(16) ushort_t vl_s[2][32 * 64];
  __shared__ float row_iz[64];
  __shared__ int   row_sub[64];
  const int tid = threadIdx.x;
  const int w = tid >> 6, lane = tid & 63;
  const int li = lane & 15, kg = lane >> 4;
  const int i0 = blockIdx.x * 64;
  const int h  = blockIdx.y;
  const int z  = blockIdx.z;
  const int b  = z & 1;
  const int jc = z >> 1;              // 0..2
  float* part = (jc == 0) ? part0 : (jc == 1) ? part1 : part2;
  const int jlo = jc * 768;           // 12 tiles of 64

  if (tid < 64) {
    const int i = i0 + tid;
    float Z = 0.f;
#pragma unroll
    for (int js = 0; js < JSPLIT; ++js)
      Z += st_z[((size_t)(js * B_ + b) * HEADS_ + h) * S_TOT + i];
    if (Z == 0.f) { row_iz[tid] = 1.0f / (float)S_TOT; row_sub[tid] = 1; }
    else          { row_iz[tid] = 1.0f / Z;            row_sub[tid] = 0; }
  }

  const ushort_t* ub = U + ((size_t)((b * 8 + h) * S_TOT + i0)) * S_TOT;
  float* pb = probs + ((size_t)((b * 8 + h) * S_TOT + i0)) * S_TOT;
  const ushort_t* vhb = VhT + ((size_t)(b * C_ + h * 32)) * S_TOT;
  const ushort_t* vlb = VlT + ((size_t)(b * C_ + h * 32)) * S_TOT;

  const int r0_  = tid >> 3,         c8_0 = tid & 7;
  const int r1_  = (tid + 256) >> 3, c8_1 = tid & 7;
  const int dr_  = tid >> 3, c8v = tid & 7;
  const size_t uo0 = (size_t)r0_ * S_TOT + c8_0 * 8 + jlo;
  const size_t uo1 = (size_t)r1_ * S_TOT + c8_1 * 8 + jlo;
  const size_t vo  = (size_t)(dr_ & 31) * S_TOT + c8v * 8 + jlo;

  f32x4 acc[2];
  acc[0] = (f32x4){0.f, 0.f, 0.f, 0.f};
  acc[1] = (f32x4){0.f, 0.f, 0.f, 0.f};

  u16x8 ur0 = __builtin_nontemporal_load((const u16x8*)(ub + uo0));
  u16x8 ur1 = __builtin_nontemporal_load((const u16x8*)(ub + uo1));
  u16x8 vhr = *(const u16x8*)(vhb + vo);
  u16x8 vlr = *(const u16x8*)(vlb + vo);
  __syncthreads();

  for (int t = 0; t < 12; ++t) {
    const int j0 = jlo + t * 64;
    const int buf = t & 1;

    {
      u16x8 uu = ur0;
      if (row_sub[r0_]) uu = (u16x8){0x3F80,0x3F80,0x3F80,0x3F80,0x3F80,0x3F80,0x3F80,0x3F80};
      float iz = row_iz[r0_];
      f32x4 p0, p1;
      p0[0] = __uint_as_float((unsigned)uu[0] << 16) * iz;
      p0[1] = __uint_as_float((unsigned)uu[1] << 16) * iz;
      p0[2] = __uint_as_float((unsigned)uu[2] << 16) * iz;
      p0[3] = __uint_as_float((unsigned)uu[3] << 16) * iz;
      p1[0] = __uint_as_float((unsigned)uu[4] << 16) * iz;
      p1[1] = __uint_as_float((unsigned)uu[5] << 16) * iz;
      p1[2] = __uint_as_float((unsigned)uu[6] << 16) * iz;
      p1[3] = __uint_as_float((unsigned)uu[7] << 16) * iz;
      float* gp = pb + (size_t)r0_ * S_TOT + j0 + c8_0 * 8;
      __builtin_nontemporal_store(p0, (f32x4*)gp);
      __builtin_nontemporal_store(p1, (f32x4*)(gp + 4));
      *(u16x8*)&u_s[buf][r0_ * 64 + (c8_0 ^ (r0_ & 7)) * 8] = uu;
    }
    {
      u16x8 uu = ur1;
      if (row_sub[r1_]) uu = (u16x8){0x3F80,0x3F80,0x3F80,0x3F80,0x3F80,0x3F80,0x3F80,0x3F80};
      float iz = row_iz[r1_];
      f32x4 p0, p1;
      p0[0] = __uint_as_float((unsigned)uu[0] << 16) * iz;
      p0[1] = __uint_as_float((unsigned)uu[1] << 16) * iz;
      p0[2] = __uint_as_float((unsigned)uu[2] << 16) * iz;
      p0[3] = __uint_as_float((unsigned)uu[3] << 16) * iz;
      p1[0] = __uint_as_float((unsigned)uu[4] << 16) * iz;
      p1[1] = __uint_as_float((unsigned)uu[5] << 16) * iz;
      p1[2] = __uint_as_float((unsigned)uu[6] << 16) * iz;
      p1[3] = __uint_as_float((unsigned)uu[7] << 16) * iz;
      float* gp = pb + (size_t)r1_ * S_TOT + j0 + c8_1 * 8;
      __builtin_nontemporal_store(p0, (f32x4*)gp);
      __builtin_nontemporal_store(p1, (f32x4*)(gp + 4));
      *(u16x8*)&u_s[buf][r1_ * 64 + (c8_1 ^ (r1_ & 7)) * 8] = uu;
    }
    *(u16x8*)&vh_s[buf][(dr_ & 31) * 64 + (c8v ^ (dr_ & 7)) * 8] = vhr;
    *(u16x8*)&vl_s[buf][(dr_ & 31) * 64 + (c8v ^ (dr_ & 7)) * 8] = vlr;

    if (t < 11) {
      const size_t j1 = (size_t)(t + 1) * 64;
      ur0 = __builtin_nontemporal_load((const u16x8*)(ub + uo0 + j1));
      ur1 = __builtin_nontemporal_load((const u16x8*)(ub + uo1 + j1));
      vhr = *(const u16x8*)(vhb + vo + j1);
      vlr = *(const u16x8*)(vlb + vo + j1);
    }
    __syncthreads();

    {
      const int row = w * 16 + li;
      const int rs = li & 7;
      s8v a0 = __builtin_bit_cast(s8v, *(const uint4*)&u_s[buf][row * 64 + ((kg)     ^ rs) * 8]);
      s8v a1 = __builtin_bit_cast(s8v, *(const uint4*)&u_s[buf][row * 64 + ((4 + kg) ^ rs) * 8]);
#pragma unroll
      for (int dh = 0; dh < 2; ++dh) {
        const int d = dh * 16 + li;
        const int ds_ = li & 7;
        s8v bh0 = __builtin_bit_cast(s8v, *(const uint4*)&vh_s[buf][d * 64 + ((kg)     ^ ds_) * 8]);
        s8v bl0 = __builtin_bit_cast(s8v, *(const uint4*)&vl_s[buf][d * 64 + ((kg)     ^ ds_) * 8]);
        s8v bh1 = __builtin_bit_cast(s8v, *(const uint4*)&vh_s[buf][d * 64 + ((4 + kg) ^ ds_) * 8]);
        s8v bl1 = __builtin_bit_cast(s8v, *(const uint4*)&vl_s[buf][d * 64 + ((4 + kg) ^ ds_) * 8]);
        acc[dh] = __builtin_amdgcn_mfma_f32_16x16x32_bf16(a0, bh0, acc[dh], 0, 0, 0);
        acc[dh] = __builtin_amdgcn_mfma_f32_16x16x32_bf16(a0, bl0, acc[dh], 0, 0, 0);
        acc[dh] = __builtin_amdgcn_mfma_f32_16x16x32_bf16(a1, bh1, acc[dh], 0, 0, 0);
        acc[dh] = __builtin_amdgcn_mfma_f32_16x16x32_bf16(a1, bl1, acc[dh], 0, 0, 0);
      }
    }
  }

  // epilogue: partial ctx (f32, iz applied) in [b][s][c] layout, nt-store
#pragma unroll
  for (int dh = 0; dh < 2; ++dh) {
#pragma unroll
    for (int reg = 0; reg < 4; ++reg) {
      const int irow = w * 16 + kg * 4 + reg;
      float v = acc[dh][reg] * row_iz[irow];
      __builtin_nontemporal_store(
          v, part + ((size_t)b * S_TOT + i0 + irow) * C_ + h * 32 + dh * 16 + li);
    }
  }
}

// ---------------------------------------------------------------------------
// Kernel 3b: ctxT hi/lo = split(part0 + part1 + part2); nt-load inputs.
// ---------------------------------------------------------------------------
__global__ __launch_bounds__(256) void k_pvred(const float* __restrict__ p0,
                                               const float* __restrict__ p1,
                                               const float* __restrict__ p2,
                                               ushort_t* __restrict__ cTh,
                                               ushort_t* __restrict__ cTl) {
  size_t i4 = ((size_t)blockIdx.x * 256 + threadIdx.x) * 4;
  f32x4 a = __builtin_nontemporal_load((const f32x4*)(p0 + i4));
  f32x4 b = __builtin_nontemporal_load((const f32x4*)(p1 + i4));
  f32x4 c = __builtin_nontemporal_load((const f32x4*)(p2 + i4));
  float v[4] = {a[0] + b[0] + c[0], a[1] + b[1] + c[1],
                a[2] + b[2] + c[2], a[3] + b[3] + c[3]};
  ushort4 hv, lv;
  ushort_t* hp = (ushort_t*)&hv;
  ushort_t* lp = (ushort_t*)&lv;
#pragma unroll
  for (int q = 0; q < 4; ++q) {
    ushort_t h = bf16_rn(v[q]);
    float hf = __uint_as_float((unsigned)h << 16);
    hp[q] = h;
    lp[q] = bf16_rn(v[q] - hf);
  }
  *(ushort4*)(cTh + i4) = hv;
  *(ushort4*)(cTl + i4) = lv;
}

// ---------------------------------------------------------------------------
// Kernel 4b: conv MFMA v2 — input pre-split/transposed bf16 [b][s][c].
// grid (8 co-tiles, 24 y-pairs, 4 = b*2+ch), block 256; ch = ci half.
// Partials written with nt-stores (read-once by act kernels).
// ---------------------------------------------------------------------------
__global__ __launch_bounds__(256) void k_conv_mfma2(
    const ushort_t* __restrict__ inTh, const ushort_t* __restrict__ inTl,
    const ushort_t* __restrict__ Wh, const ushort_t* __restrict__ Wl,
    float* __restrict__ part0, float* __restrict__ part1) {
  __shared__ __align__(16) ushort_t in_sh[4 * 50 * 40];
  __shared__ __align__(16) ushort_t in_sl[4 * 50 * 40];
  const int tid = threadIdx.x;
  const int w = tid >> 6, lane = tid & 63;
  const int li = lane & 15, kg = lane >> 4;
  const int cg = w & 1, rw = w >> 1;
  const int co0 = blockIdx.x * 32;
  const int y0  = blockIdx.y * 2;
  const int z   = blockIdx.z;
  const int b = z >> 1, ch = z & 1;
  float* part = ch ? part1 : part0;

  for (int e = tid; e < 320; e += 256) {
    int sr = e / 80, rem = e % 80;
    int xl = (rem / 40) * 49, ci = rem % 40;
    in_sh[(sr * 50 + xl) * 40 + ci] = 0;
    in_sl[(sr * 50 + xl) * 40 + ci] = 0;
  }

  f32x4 acc[3];
#pragma unroll
  for (int xg = 0; xg < 3; ++xg) acc[xg] = (f32x4){0.f, 0.f, 0.f, 0.f};

  for (int c8 = 0; c8 < 4; ++c8) {
    const int ci0 = ch * 128 + c8 * 32;
    __syncthreads();
#pragma unroll
    for (int t = 0; t < 3; ++t) {
      int id = t * 256 + tid;
      int cig = id & 3;
      int xx  = (id >> 2) % 48;
      int sr  = id / 192;
      int gr  = y0 - 1 + sr;
      u16x8 vh = {0,0,0,0,0,0,0,0}, vl = {0,0,0,0,0,0,0,0};
      if (gr >= 0 && gr < 48) {
        size_t go = ((size_t)b * S_TOT + gr * 48 + xx) * C_ + ci0 + cig * 8;
        vh = *(const u16x8*)(inTh + go);
        vl = *(const u16x8*)(inTl + go);
      }
      int lo = (sr * 50 + xx + 1) * 40 + cig * 8;
      *(u16x8*)&in_sh[lo] = vh;
      *(u16x8*)&in_sl[lo] = vl;
    }
    __syncthreads();

#pragma unroll
    for (int ky = 0; ky < 3; ++ky) {
      const int srr = rw + ky;
#pragma unroll
      for (int kx = 0; kx < 3; ++kx) {
        const int tap = ky * 3 + kx;
        size_t wo = ((size_t)tap * 256 + co0 + cg * 16 + li) * 256 + ci0 + kg * 8;
        s8v ah = __builtin_bit_cast(s8v, *(const uint4*)(Wh + wo));
        s8v al = __builtin_bit_cast(s8v, *(const uint4*)(Wl + wo));
#pragma unroll
        for (int xg = 0; xg < 3; ++xg) {
          const int xl = xg * 16 + li + kx;
          s8v bh = __builtin_bit_cast(s8v, *(const uint4*)&in_sh[(srr * 50 + xl) * 40 + kg * 8]);
          s8v bl = __builtin_bit_cast(s8v, *(const uint4*)&in_sl[(srr * 50 + xl) * 40 + kg * 8]);
          acc[xg] = __builtin_amdgcn_mfma_f32_16x16x32_bf16(ah, bh, acc[xg], 0, 0, 0);
          acc[xg] = __builtin_amdgcn_mfma_f32_16x16x32_bf16(ah, bl, acc[xg], 0, 0, 0);
          acc[xg] = __builtin_amdgcn_mfma_f32_16x16x32_bf16(al, bh, acc[xg], 0, 0, 0);
        }
      }
    }
  }

  const int orow = y0 + rw;
#pragma unroll
  for (int reg = 0; reg < 4; ++reg) {
    const int co = co0 + cg * 16 + kg * 4 + reg;
    float* op = part + ((size_t)(b * 256 + co) * 48 + orow) * 48 + li;
#pragma unroll
    for (int xg = 0; xg < 3; ++xg)
      __builtin_nontemporal_store(acc[xg][reg], op + xg * 16);
  }
}

// ---------------------------------------------------------------------------
// Kernel 4c: y = selu(Cp0+Cp1+bias), transpose+split -> t1T hi/lo [b][s][c].
// grid (36 s-tiles, 4 co-tiles, B). nt-load partials.
// ---------------------------------------------------------------------------
__global__ __launch_bounds__(256) void k_act_t(const float* __restrict__ p0,
                                               const float* __restrict__ p1,
                                               const float* __restrict__ bias,
                                               ushort_t* __restrict__ outTh,
                                               ushort_t* __restrict__ outTl) {
  __shared__ __align__(16) float t_s[64][65];
  const int tid = threadIdx.x;
  const int s0 = blockIdx.x * 64;
  const int co0 = blockIdx.y * 64;
  const int b  = blockIdx.z;

#pragma unroll
  for (int k = 0; k < 16; ++k) {
    int idx = tid + k * 256;
    int r = idx >> 6, c = idx & 63;
    size_t a = ((size_t)(b * 256 + co0 + r)) * S_TOT + s0 + c;
    float v = __builtin_nontemporal_load(p0 + a) +
              __builtin_nontemporal_load(p1 + a) + bias[co0 + r];
    v = 1.0507009873554805f * (v > 0.f ? v : 1.6732632423543772f * expm1f(v));
    t_s[r][c] = v;
  }
  __syncthreads();
#pragma unroll
  for (int k = 0; k < 16; ++k) {
    int idx = tid + k * 256;
    int p = idx >> 6, c = idx & 63;
    float v = t_s[c][p];
    ushort_t h = bf16_rn(v);
    float hf = __uint_as_float((unsigned)h << 16);
    ushort_t l = bf16_rn(v - hf);
    size_t o = ((size_t)b * S_TOT + s0 + p) * C_ + co0 + c;
    outTh[o] = h;
    outTl[o] = l;
  }
}

// ---------------------------------------------------------------------------
// Kernel 4d: out = Cp0 + Cp1 + bias (f32, no act); nt in and out.
// ---------------------------------------------------------------------------
__global__ __launch_bounds__(256) void k_act2(const float* __restrict__ p0,
                                              const float* __restrict__ p1,
                                              const float* __restrict__ bias,
                                              float* __restrict__ out) {
  size_t i4 = ((size_t)blockIdx.x * 256 + threadIdx.x) * 4;
  f32x4 a = __builtin_nontemporal_load((const f32x4*)(p0 + i4));
  f32x4 b = __builtin_nontemporal_load((const f32x4*)(p1 + i4));
  int co = (int)((i4 / (size_t)S_TOT) & 255);
  float bi = bias[co];
  f32x4 o;
  o[0] = a[0] + b[0] + bi; o[1] = a[1] + b[1] + bi;
  o[2] = a[2] + b[2] + bi; o[3] = a[3] + b[3] + bi;
  __builtin_nontemporal_store(o, (f32x4*)(out + i4));
}

// ---------------------------------------------------------------------------
extern "C" void kernel_launch(void* const* d_in, const int* in_sizes, int n_in,
                              void* d_out, int out_size, void* d_ws, size_t ws_size,
                              hipStream_t stream) {
  const float* x   = (const float*)d_in[0];
  const float* ref = (const float*)d_in[1];
  const float* qW1 = (const float*)d_in[2];
  const float* qb1 = (const float*)d_in[3];
  const float* qW2 = (const float*)d_in[4];
  const float* qb2 = (const float*)d_in[5];
  const float* kW1 = (const float*)d_in[6];
  const float* kb1 = (const float*)d_in[7];
  const float* kW2 = (const float*)d_in[8];
  const float* kb2 = (const float*)d_in[9];
  const float* vW1 = (const float*)d_in[10];
  const float* vb1 = (const float*)d_in[11];
  const float* vW2 = (const float*)d_in[12];
  const float* vb2 = (const float*)d_in[13];
  const float* c1W = (const float*)d_in[14];
  const float* c1b = (const float*)d_in[15];
  const float* c2W = (const float*)d_in[16];
  const float* c2b = (const float*)d_in[17];

  float* out = (float*)d_out;
  float* probs = out + (size_t)B_ * C_ * S_TOT;       // [B][H][S][S]
  float* ws = (float*)d_ws;
  const size_t BSC = (size_t)B_ * S_TOT * C_;         // 1,179,648
  const size_t STATS = (size_t)JSPLIT * B_ * HEADS_ * S_TOT;
  const size_t WTSZ = (size_t)256 * 9 * 256;

  float* stz = ws;
  float* Pv0 = stz + STATS;
  float* Pv1 = Pv0 + BSC;
  float* Pv2 = Pv1 + BSC;
  float* endf = Pv2 + BSC;

  ushort_t* Qh  = (ushort_t*)endf;
  ushort_t* Ql  = Qh + BSC;
  ushort_t* Kh  = Ql + BSC;
  ushort_t* Kl  = Kh + BSC;
  ushort_t* VhT = Kl + BSC;
  ushort_t* VlT = VhT + BSC;
  ushort_t* cTh = VlT + BSC;
  ushort_t* cTl = cTh + BSC;
  ushort_t* t1h = cTl + BSC;
  ushort_t* t1l = t1h + BSC;
  ushort_t* Wh1 = t1l + BSC;
  ushort_t* Wl1 = Wh1 + WTSZ;
  ushort_t* Wh2 = Wl1 + WTSZ;
  ushort_t* Wl2 = Wh2 + WTSZ;
  ushort_t* Ubuf = Wl2 + WTSZ;   // ~170 MB

  // conv partials reuse Pv0/Pv1 (dead after pvred)
  float* Cp0 = Pv0;
  float* Cp1 = Pv1;

  dim3 blk(256);
  k_mlpf<<<dim3(72, B_, 4), blk, 0, stream>>>(x, ref,
                                              qW1, qb1, qW2, qb2,
                                              kW1, kb1, kW2, kb2,
                                              vW1, vb1, vW2, vb2,
                                              c1W, c2W,
                                              Qh, Ql, Kh, Kl, VhT, VlT,
                                              Wh1, Wl1, Wh2, Wl2);

  k_scores_mfma<<<dim3(36, JSPLIT, B_), blk, 0, stream>>>(Qh, Ql, Kh, Kl, Ubuf, stz);

  k_pv5<<<dim3(36, 8, 6), blk, 0, stream>>>(Ubuf, stz, VhT, VlT, probs, Pv0, Pv1, Pv2);
  k_pvred<<<dim3((int)(BSC / 1024)), blk, 0, stream>>>(Pv0, Pv1, Pv2, cTh, cTl);

  dim3 gconv(8, 24, 2 * B_);
  k_conv_mfma2<<<gconv, blk, 0, stream>>>(cTh, cTl, Wh1, Wl1, Cp0, Cp1);
  k_act_t<<<dim3(36, 4, B_), blk, 0, stream>>>(Cp0, Cp1, c1b, t1h, t1l);
  k_conv_mfma2<<<gconv, blk, 0, stream>>>(t1h, t1l, Wh2, Wl2, Cp0, Cp1);
  k_act2<<<dim3((int)(BSC / 1024)), blk, 0, stream>>>(Cp0, Cp1, c2b, out);
}

// Round 17
// 386.245 us; speedup vs baseline: 1.0974x; 1.0974x over previous
//
#include <hip/hip_runtime.h>
#include <hip/hip_bf16.h>

typedef unsigned short ushort_t;
typedef short s8v __attribute__((ext_vector_type(8)));      // 8 bf16 bit-patterns
typedef ushort_t u16x8 __attribute__((ext_vector_type(8))); // 8 ushorts (16B)
typedef float f32x4 __attribute__((ext_vector_type(4)));

// Problem constants
constexpr int B_ = 2;
constexpr int C_ = 256;
constexpr int S_TOT = 48 * 48;   // 2304
constexpr int HEADS_ = 8;
constexpr int JSPLIT = 12;       // scores j-chunks (Z partials)
#define INV_SQRT_DH 0.17677669529663688f

__device__ __forceinline__ ushort_t bf16_rn(float x) {
  unsigned u = __float_as_uint(x);
  return (ushort_t)((u + 0x7fffu + ((u >> 16) & 1u)) >> 16);
}

// ---------------------------------------------------------------------------
// Kernel 1 (fused both MLP layers x3 tensors + conv-weight repack plane):
// z=0: Q [b][s][C]; z=1: K [b][s][C]; z=2: V^T [b][C][s];
// z=3: repack+split conv weights (b selects conv1/conv2).
// grid (72, B, 4), block 256.
// ---------------------------------------------------------------------------
__global__ __launch_bounds__(256) void k_mlpf(
    const float* __restrict__ x, const float* __restrict__ ref,
    const float* __restrict__ qW1, const float* __restrict__ qb1,
    const float* __restrict__ qW2, const float* __restrict__ qb2,
    const float* __restrict__ kW1, const float* __restrict__ kb1,
    const float* __restrict__ kW2, const float* __restrict__ kb2,
    const float* __restrict__ vW1, const float* __restrict__ vb1,
    const float* __restrict__ vW2, const float* __restrict__ vb2,
    const float* __restrict__ c1W, const float* __restrict__ c2W,
    ushort_t* __restrict__ Qh, ushort_t* __restrict__ Ql,
    ushort_t* __restrict__ Kh, ushort_t* __restrict__ Kl,
    ushort_t* __restrict__ VhT, ushort_t* __restrict__ VlT,
    ushort_t* __restrict__ Wh1, ushort_t* __restrict__ Wl1,
    ushort_t* __restrict__ Wh2, ushort_t* __restrict__ Wl2) {
  __shared__ __align__(16) float in_s[32][260];
  __shared__ __align__(16) float h_s[32][260];
  const int tid = threadIdx.x;
  const int b  = blockIdx.y;
  const int z  = blockIdx.z;

  if (z == 3) {
    const float* W = b ? c2W : c1W;
    ushort_t* Wh = b ? Wh2 : Wh1;
    ushort_t* Wl = b ? Wl2 : Wl1;
    const int ci = tid;
#pragma unroll 4
    for (int k = 0; k < 32; ++k) {
      int p = blockIdx.x * 32 + k;
      int co = p / 9, tap = p - co * 9;
      float v = W[((size_t)co * 256 + ci) * 9 + tap];
      ushort_t h = bf16_rn(v);
      float r = __uint_as_float((unsigned)h << 16);
      ushort_t l = bf16_rn(v - r);
      size_t o = ((size_t)tap * 256 + co) * 256 + ci;
      Wh[o] = h;
      Wl[o] = l;
    }
    return;
  }

  const int s0 = blockIdx.x * 32;
  const float* in = (z == 0) ? x : ref;
  const float* W1 = (z == 0) ? qW1 : (z == 1) ? kW1 : vW1;
  const float* b1 = (z == 0) ? qb1 : (z == 1) ? kb1 : vb1;
  const float* W2 = (z == 0) ? qW2 : (z == 1) ? kW2 : vW2;
  const float* b2 = (z == 0) ? qb2 : (z == 1) ? kb2 : vb2;

  for (int idx = tid; idx < 32 * 256; idx += 256) {
    int ci = idx >> 5, r = idx & 31;
    in_s[r][ci] = in[((size_t)b * C_ + ci) * S_TOT + s0 + r];
  }
  __syncthreads();

  const int co = tid;
  float acc[32];
#pragma unroll
  for (int r = 0; r < 32; ++r) acc[r] = 0.f;
  for (int c4 = 0; c4 < 64; ++c4) {
    const float w0 = W1[(c4 * 4 + 0) * C_ + co];
    const float w1 = W1[(c4 * 4 + 1) * C_ + co];
    const float w2 = W1[(c4 * 4 + 2) * C_ + co];
    const float w3 = W1[(c4 * 4 + 3) * C_ + co];
#pragma unroll
    for (int r = 0; r < 32; ++r) {
      float4 a = *(const float4*)&in_s[r][c4 * 4];
      acc[r] = fmaf(a.x, w0, fmaf(a.y, w1, fmaf(a.z, w2, fmaf(a.w, w3, acc[r]))));
    }
  }
  {
    const float bi = b1[co];
#pragma unroll
    for (int r = 0; r < 32; ++r) h_s[r][co] = fmaxf(acc[r] + bi, 0.f);
  }
  __syncthreads();

#pragma unroll
  for (int r = 0; r < 32; ++r) acc[r] = 0.f;
  for (int c4 = 0; c4 < 64; ++c4) {
    const float w0 = W2[(c4 * 4 + 0) * C_ + co];
    const float w1 = W2[(c4 * 4 + 1) * C_ + co];
    const float w2 = W2[(c4 * 4 + 2) * C_ + co];
    const float w3 = W2[(c4 * 4 + 3) * C_ + co];
#pragma unroll
    for (int r = 0; r < 32; ++r) {
      float4 a = *(const float4*)&h_s[r][c4 * 4];
      acc[r] = fmaf(a.x, w0, fmaf(a.y, w1, fmaf(a.z, w2, fmaf(a.w, w3, acc[r]))));
    }
  }
  const float bi = b2[co];

  if (z < 2) {
    ushort_t* Ph = (z == 0) ? Qh : Kh;
    ushort_t* Pl = (z == 0) ? Ql : Kl;
#pragma unroll 4
    for (int r = 0; r < 32; ++r) {
      float y = fmaxf(acc[r] + bi, 0.f);
      ushort_t h = bf16_rn(y);
      float hf = __uint_as_float((unsigned)h << 16);
      ushort_t l = bf16_rn(y - hf);
      size_t o = ((size_t)b * S_TOT + s0 + r) * C_ + co;
      Ph[o] = h;
      Pl[o] = l;
    }
  } else {
    ushort_t hs[32], ls[32];
#pragma unroll
    for (int r = 0; r < 32; ++r) {
      float y = fmaxf(acc[r] + bi, 0.f);
      ushort_t h = bf16_rn(y);
      float hf = __uint_as_float((unsigned)h << 16);
      hs[r] = h;
      ls[r] = bf16_rn(y - hf);
    }
    size_t base = ((size_t)b * C_ + co) * S_TOT + s0;
#pragma unroll
    for (int k = 0; k < 4; ++k) {
      u16x8 hv, lv;
#pragma unroll
      for (int q = 0; q < 8; ++q) { hv[q] = hs[k * 8 + q]; lv[q] = ls[k * 8 + q]; }
      *(u16x8*)(VhT + base + k * 8) = hv;
      *(u16x8*)(VlT + base + k * 8) = lv;
    }
  }
}

// ---------------------------------------------------------------------------
// Kernel 2 (MFMA): scores + top-1-over-heads mask -> U bf16 + Z partials.
// grid (36, JSPLIT=12, B) = 864 blocks; K in 3 tiles of 64 rows (64 KiB);
// natural VGPR (no cap — round-3/12 spill lesson). U stores batched via
// 16 KB LDS buffer (round-14 win). LDS total 80 KiB -> 2 blocks/CU.
// ---------------------------------------------------------------------------
__global__ __launch_bounds__(256) void k_scores_mfma(
    const ushort_t* __restrict__ Qh, const ushort_t* __restrict__ Ql,
    const ushort_t* __restrict__ Kh, const ushort_t* __restrict__ Kl,
    ushort_t* __restrict__ U, float* __restrict__ st_z) {
  __shared__ __align__(16) uint4 kh_s[64 * 32];        // 32 KB
  __shared__ __align__(16) uint4 kl_s[64 * 32];        // 32 KB
  __shared__ __align__(16) ushort_t u_ls[8 * 64 * 16]; // 16 KB (one jsub tile)
  const int tid = threadIdx.x;
  const int w = tid >> 6, lane = tid & 63;
  const int li = lane & 15, kg = lane >> 4;
  const int i0 = blockIdx.x * 64;
  const int js = blockIdx.y;          // 0..11
  const int b  = blockIdx.z;
  const int jbase = js * 192;         // 3 j-tiles of 64 per chunk

  s8v ahi[8], alo[8];
  {
    const ushort_t* qh = Qh + ((size_t)b * S_TOT + i0 + w * 16 + li) * C_ + kg * 8;
    const ushort_t* ql = Ql + ((size_t)b * S_TOT + i0 + w * 16 + li) * C_ + kg * 8;
#pragma unroll
    for (int h = 0; h < 8; ++h) {
      ahi[h] = __builtin_bit_cast(s8v, *(const uint4*)(qh + h * 32));
      alo[h] = __builtin_bit_cast(s8v, *(const uint4*)(ql + h * 32));
    }
  }

  float zacc[4][8];
#pragma unroll
  for (int r = 0; r < 4; ++r)
#pragma unroll
    for (int h = 0; h < 8; ++h) zacc[r][h] = 0.f;

  for (int jt = 0; jt < 3; ++jt) {
    const int j0 = jbase + jt * 64;
    for (int e = tid; e < 2048; e += 256) {
      int r = e >> 5, c = e & 31;
      size_t goff = ((size_t)b * S_TOT + j0 + r) * C_ + c * 8;
      int cs = c ^ (r & 7);
      kh_s[r * 32 + cs] = *(const uint4*)(Kh + goff);
      kl_s[r * 32 + cs] = *(const uint4*)(Kl + goff);
    }
    __syncthreads();

#pragma unroll
    for (int jsub = 0; jsub < 4; ++jsub) {
      const int rj = jsub * 16 + li;
      f32x4 sc[8];
#pragma unroll
      for (int h = 0; h < 8; ++h) {
        const int cs = (h * 4 + kg) ^ (rj & 7);
        s8v bhi = __builtin_bit_cast(s8v, kh_s[rj * 32 + cs]);
        s8v blo = __builtin_bit_cast(s8v, kl_s[rj * 32 + cs]);
        f32x4 acc = {0.f, 0.f, 0.f, 0.f};
        acc = __builtin_amdgcn_mfma_f32_16x16x32_bf16(ahi[h], bhi, acc, 0, 0, 0);
        acc = __builtin_amdgcn_mfma_f32_16x16x32_bf16(ahi[h], blo, acc, 0, 0, 0);
        acc = __builtin_amdgcn_mfma_f32_16x16x32_bf16(alo[h], bhi, acc, 0, 0, 0);
        sc[h] = acc;
      }
#pragma unroll
      for (int reg = 0; reg < 4; ++reg) {
        float s8_[8];
        float thr = -1e30f;
#pragma unroll
        for (int h = 0; h < 8; ++h) {
          s8_[h] = sc[h][reg] * INV_SQRT_DH;
          thr = fmaxf(thr, s8_[h]);
        }
        const int il = w * 16 + kg * 4 + reg;
#pragma unroll
        for (int h = 0; h < 8; ++h) {
          float mv = s8_[h] < thr ? -1e18f : s8_[h];
          float uf = __expf(mv);            // 0 exactly when masked
          ushort_t ub = bf16_rn(uf);
          u_ls[(h * 64 + il) * 16 + li] = ub;
          zacc[reg][h] += __uint_as_float((unsigned)ub << 16);
        }
      }
      __syncthreads();   // u_ls writes visible
#pragma unroll
      for (int k = 0; k < 4; ++k) {
        int c = tid + k * 256;
        int h = c >> 7, ii = (c >> 1) & 63, jh = c & 1;
        u16x8 v = *(const u16x8*)&u_ls[(h * 64 + ii) * 16 + jh * 8];
        *(u16x8*)(U + ((size_t)((b * 8 + h) * S_TOT + i0 + ii)) * S_TOT
                    + j0 + jsub * 16 + jh * 8) = v;
      }
      __syncthreads();   // u_ls reads done before next jsub overwrites
    }
  }

#pragma unroll
  for (int reg = 0; reg < 4; ++reg) {
#pragma unroll
    for (int h = 0; h < 8; ++h) {
      float z = zacc[reg][h];
      z += __shfl_xor(z, 1);
      z += __shfl_xor(z, 2);
      z += __shfl_xor(z, 4);
      z += __shfl_xor(z, 8);
      if (li == 0) {
        const int i = i0 + w * 16 + kg * 4 + reg;
        size_t sidx = ((size_t)(js * B_ + b) * HEADS_ + h) * S_TOT + i;
        st_z[sidx] = z;
      }
    }
  }
}

// ---------------------------------------------------------------------------
// Kernel 3: probs = U/Z + partial ctx via bf16 MFMA, j-split 3-way.
// grid (36 i-tiles, 8 h, 6 = jc*2+b) = 1728 blocks, block 256.
// probs written via NONTEMPORAL stores (never re-read on device — the ONLY
// nt stream; round-16 lesson: nt on producer->consumer intermediates
// forces HBM round-trips the cache would absorb).
// ---------------------------------------------------------------------------
__global__ __launch_bounds__(256) void k_pv5(const ushort_t* __restrict__ U,
                                             const float* __restrict__ st_z,
                                             const ushort_t* __restrict__ VhT,
                                             const ushort_t* __restrict__ VlT,
                                             float* __restrict__ probs,
                                             float* __restrict__ part0,
                                             float* __restrict__ part1,
                                             float* __restrict__ part2) {
  __shared__ __align__(16) ushort_t u_s[2][64 * 64];
  __shared__ __align__(16) ushort_t vh_s[2][32 * 64];
  __shared__ __align__(16) ushort_t vl_s[2][32 * 64];
  __shared__ float row_iz[64];
  __shared__ int   row_sub[64];
  const int tid = threadIdx.x;
  const int w = tid >> 6, lane = tid & 63;
  const int li = lane & 15, kg = lane >> 4;
  const int i0 = blockIdx.x * 64;
  const int h  = blockIdx.y;
  const int z  = blockIdx.z;
  const int b  = z & 1;
  const int jc = z >> 1;              // 0..2
  float* part = (jc == 0) ? part0 : (jc == 1) ? part1 : part2;
  const int jlo = jc * 768;           // 12 tiles of 64

  if (tid < 64) {
    const int i = i0 + tid;
    float Z = 0.f;
#pragma unroll
    for (int js = 0; js < JSPLIT; ++js)
      Z += st_z[((size_t)(js * B_ + b) * HEADS_ + h) * S_TOT + i];
    if (Z == 0.f) { row_iz[tid] = 1.0f / (float)S_TOT; row_sub[tid] = 1; }
    else          { row_iz[tid] = 1.0f / Z;            row_sub[tid] = 0; }
  }

  const ushort_t* ub = U + ((size_t)((b * 8 + h) * S_TOT + i0)) * S_TOT;
  float* pb = probs + ((size_t)((b * 8 + h) * S_TOT + i0)) * S_TOT;
  const ushort_t* vhb = VhT + ((size_t)(b * C_ + h * 32)) * S_TOT;
  const ushort_t* vlb = VlT + ((size_t)(b * C_ + h * 32)) * S_TOT;

  const int r0_  = tid >> 3,         c8_0 = tid & 7;
  const int r1_  = (tid + 256) >> 3, c8_1 = tid & 7;
  const int dr_  = tid >> 3, c8v = tid & 7;
  const size_t uo0 = (size_t)r0_ * S_TOT + c8_0 * 8 + jlo;
  const size_t uo1 = (size_t)r1_ * S_TOT + c8_1 * 8 + jlo;
  const size_t vo  = (size_t)(dr_ & 31) * S_TOT + c8v * 8 + jlo;

  f32x4 acc[2];
  acc[0] = (f32x4){0.f, 0.f, 0.f, 0.f};
  acc[1] = (f32x4){0.f, 0.f, 0.f, 0.f};

  u16x8 ur0 = *(const u16x8*)(ub + uo0);
  u16x8 ur1 = *(const u16x8*)(ub + uo1);
  u16x8 vhr = *(const u16x8*)(vhb + vo);
  u16x8 vlr = *(const u16x8*)(vlb + vo);
  __syncthreads();

  for (int t = 0; t < 12; ++t) {
    const int j0 = jlo + t * 64;
    const int buf = t & 1;

    {
      u16x8 uu = ur0;
      if (row_sub[r0_]) uu = (u16x8){0x3F80,0x3F80,0x3F80,0x3F80,0x3F80,0x3F80,0x3F80,0x3F80};
      float iz = row_iz[r0_];
      f32x4 p0, p1;
      p0[0] = __uint_as_float((unsigned)uu[0] << 16) * iz;
      p0[1] = __uint_as_float((unsigned)uu[1] << 16) * iz;
      p0[2] = __uint_as_float((unsigned)uu[2] << 16) * iz;
      p0[3] = __uint_as_float((unsigned)uu[3] << 16) * iz;
      p1[0] = __uint_as_float((unsigned)uu[4] << 16) * iz;
      p1[1] = __uint_as_float((unsigned)uu[5] << 16) * iz;
      p1[2] = __uint_as_float((unsigned)uu[6] << 16) * iz;
      p1[3] = __uint_as_float((unsigned)uu[7] << 16) * iz;
      float* gp = pb + (size_t)r0_ * S_TOT + j0 + c8_0 * 8;
      __builtin_nontemporal_store(p0, (f32x4*)gp);
      __builtin_nontemporal_store(p1, (f32x4*)(gp + 4));
      *(u16x8*)&u_s[buf][r0_ * 64 + (c8_0 ^ (r0_ & 7)) * 8] = uu;
    }
    {
      u16x8 uu = ur1;
      if (row_sub[r1_]) uu = (u16x8){0x3F80,0x3F80,0x3F80,0x3F80,0x3F80,0x3F80,0x3F80,0x3F80};
      float iz = row_iz[r1_];
      f32x4 p0, p1;
      p0[0] = __uint_as_float((unsigned)uu[0] << 16) * iz;
      p0[1] = __uint_as_float((unsigned)uu[1] << 16) * iz;
      p0[2] = __uint_as_float((unsigned)uu[2] << 16) * iz;
      p0[3] = __uint_as_float((unsigned)uu[3] << 16) * iz;
      p1[0] = __uint_as_float((unsigned)uu[4] << 16) * iz;
      p1[1] = __uint_as_float((unsigned)uu[5] << 16) * iz;
      p1[2] = __uint_as_float((unsigned)uu[6] << 16) * iz;
      p1[3] = __uint_as_float((unsigned)uu[7] << 16) * iz;
      float* gp = pb + (size_t)r1_ * S_TOT + j0 + c8_1 * 8;
      __builtin_nontemporal_store(p0, (f32x4*)gp);
      __builtin_nontemporal_store(p1, (f32x4*)(gp + 4));
      *(u16x8*)&u_s[buf][r1_ * 64 + (c8_1 ^ (r1_ & 7)) * 8] = uu;
    }
    *(u16x8*)&vh_s[buf][(dr_ & 31) * 64 + (c8v ^ (dr_ & 7)) * 8] = vhr;
    *(u16x8*)&vl_s[buf][(dr_ & 31) * 64 + (c8v ^ (dr_ & 7)) * 8] = vlr;

    if (t < 11) {
      const size_t j1 = (size_t)(t + 1) * 64;
      ur0 = *(const u16x8*)(ub + uo0 + j1);
      ur1 = *(const u16x8*)(ub + uo1 + j1);
      vhr = *(const u16x8*)(vhb + vo + j1);
      vlr = *(const u16x8*)(vlb + vo + j1);
    }
    __syncthreads();

    {
      const int row = w * 16 + li;
      const int rs = li & 7;
      s8v a0 = __builtin_bit_cast(s8v, *(const uint4*)&u_s[buf][row * 64 + ((kg)     ^ rs) * 8]);
      s8v a1 = __builtin_bit_cast(s8v, *(const uint4*)&u_s[buf][row * 64 + ((4 + kg) ^ rs) * 8]);
#pragma unroll
      for (int dh = 0; dh < 2; ++dh) {
        const int d = dh * 16 + li;
        const int ds_ = li & 7;
        s8v bh0 = __builtin_bit_cast(s8v, *(const uint4*)&vh_s[buf][d * 64 + ((kg)     ^ ds_) * 8]);
        s8v bl0 = __builtin_bit_cast(s8v, *(const uint4*)&vl_s[buf][d * 64 + ((kg)     ^ ds_) * 8]);
        s8v bh1 = __builtin_bit_cast(s8v, *(const uint4*)&vh_s[buf][d * 64 + ((4 + kg) ^ ds_) * 8]);
        s8v bl1 = __builtin_bit_cast(s8v, *(const uint4*)&vl_s[buf][d * 64 + ((4 + kg) ^ ds_) * 8]);
        acc[dh] = __builtin_amdgcn_mfma_f32_16x16x32_bf16(a0, bh0, acc[dh], 0, 0, 0);
        acc[dh] = __builtin_amdgcn_mfma_f32_16x16x32_bf16(a0, bl0, acc[dh], 0, 0, 0);
        acc[dh] = __builtin_amdgcn_mfma_f32_16x16x32_bf16(a1, bh1, acc[dh], 0, 0, 0);
        acc[dh] = __builtin_amdgcn_mfma_f32_16x16x32_bf16(a1, bl1, acc[dh], 0, 0, 0);
      }
    }
  }

  // epilogue: partial ctx (f32, iz applied) in [b][s][c] layout (plain store
  // — read by k_pvred soon after; cache-resident)
#pragma unroll
  for (int dh = 0; dh < 2; ++dh) {
#pragma unroll
    for (int reg = 0; reg < 4; ++reg) {
      const int irow = w * 16 + kg * 4 + reg;
      float v = acc[dh][reg] * row_iz[irow];
      part[((size_t)b * S_TOT + i0 + irow) * C_ + h * 32 + dh * 16 + li] = v;
    }
  }
}

// ---------------------------------------------------------------------------
// Kernel 3b: ctxT hi/lo = split(part0 + part1 + part2) (elementwise)
// ---------------------------------------------------------------------------
__global__ __launch_bounds__(256) void k_pvred(const float* __restrict__ p0,
                                               const float* __restrict__ p1,
                                               const float* __restrict__ p2,
                                               ushort_t* __restrict__ cTh,
                                               ushort_t* __restrict__ cTl) {
  size_t i4 = ((size_t)blockIdx.x * 256 + threadIdx.x) * 4;
  float4 a = *(const float4*)(p0 + i4);
  float4 b = *(const float4*)(p1 + i4);
  float4 c = *(const float4*)(p2 + i4);
  float v[4] = {a.x + b.x + c.x, a.y + b.y + c.y, a.z + b.z + c.z, a.w + b.w + c.w};
  ushort4 hv, lv;
  ushort_t* hp = (ushort_t*)&hv;
  ushort_t* lp = (ushort_t*)&lv;
#pragma unroll
  for (int q = 0; q < 4; ++q) {
    ushort_t h = bf16_rn(v[q]);
    float hf = __uint_as_float((unsigned)h << 16);
    hp[q] = h;
    lp[q] = bf16_rn(v[q] - hf);
  }
  *(ushort4*)(cTh + i4) = hv;
  *(ushort4*)(cTl + i4) = lv;
}

// ---------------------------------------------------------------------------
// Kernel 4b: conv MFMA v2 — input pre-split/transposed bf16 [b][s][c].
// grid (8 co-tiles, 24 y-pairs, 4 = b*2+ch), block 256; ch = ci half.
// ---------------------------------------------------------------------------
__global__ __launch_bounds__(256) void k_conv_mfma2(
    const ushort_t* __restrict__ inTh, const ushort_t* __restrict__ inTl,
    const ushort_t* __restrict__ Wh, const ushort_t* __restrict__ Wl,
    float* __restrict__ part0, float* __restrict__ part1) {
  __shared__ __align__(16) ushort_t in_sh[4 * 50 * 40];
  __shared__ __align__(16) ushort_t in_sl[4 * 50 * 40];
  const int tid = threadIdx.x;
  const int w = tid >> 6, lane = tid & 63;
  const int li = lane & 15, kg = lane >> 4;
  const int cg = w & 1, rw = w >> 1;
  const int co0 = blockIdx.x * 32;
  const int y0  = blockIdx.y * 2;
  const int z   = blockIdx.z;
  const int b = z >> 1, ch = z & 1;
  float* part = ch ? part1 : part0;

  for (int e = tid; e < 320; e += 256) {
    int sr = e / 80, rem = e % 80;
    int xl = (rem / 40) * 49, ci = rem % 40;
    in_sh[(sr * 50 + xl) * 40 + ci] = 0;
    in_sl[(sr * 50 + xl) * 40 + ci] = 0;
  }

  f32x4 acc[3];
#pragma unroll
  for (int xg = 0; xg < 3; ++xg) acc[xg] = (f32x4){0.f, 0.f, 0.f, 0.f};

  for (int c8 = 0; c8 < 4; ++c8) {
    const int ci0 = ch * 128 + c8 * 32;
    __syncthreads();
#pragma unroll
    for (int t = 0; t < 3; ++t) {
      int id = t * 256 + tid;
      int cig = id & 3;
      int xx  = (id >> 2) % 48;
      int sr  = id / 192;
      int gr  = y0 - 1 + sr;
      u16x8 vh = {0,0,0,0,0,0,0,0}, vl = {0,0,0,0,0,0,0,0};
      if (gr >= 0 && gr < 48) {
        size_t go = ((size_t)b * S_TOT + gr * 48 + xx) * C_ + ci0 + cig * 8;
        vh = *(const u16x8*)(inTh + go);
        vl = *(const u16x8*)(inTl + go);
      }
      int lo = (sr * 50 + xx + 1) * 40 + cig * 8;
      *(u16x8*)&in_sh[lo] = vh;
      *(u16x8*)&in_sl[lo] = vl;
    }
    __syncthreads();

#pragma unroll
    for (int ky = 0; ky < 3; ++ky) {
      const int srr = rw + ky;
#pragma unroll
      for (int kx = 0; kx < 3; ++kx) {
        const int tap = ky * 3 + kx;
        size_t wo = ((size_t)tap * 256 + co0 + cg * 16 + li) * 256 + ci0 + kg * 8;
        s8v ah = __builtin_bit_cast(s8v, *(const uint4*)(Wh + wo));
        s8v al = __builtin_bit_cast(s8v, *(const uint4*)(Wl + wo));
#pragma unroll
        for (int xg = 0; xg < 3; ++xg) {
          const int xl = xg * 16 + li + kx;
          s8v bh = __builtin_bit_cast(s8v, *(const uint4*)&in_sh[(srr * 50 + xl) * 40 + kg * 8]);
          s8v bl = __builtin_bit_cast(s8v, *(const uint4*)&in_sl[(srr * 50 + xl) * 40 + kg * 8]);
          acc[xg] = __builtin_amdgcn_mfma_f32_16x16x32_bf16(ah, bh, acc[xg], 0, 0, 0);
          acc[xg] = __builtin_amdgcn_mfma_f32_16x16x32_bf16(ah, bl, acc[xg], 0, 0, 0);
          acc[xg] = __builtin_amdgcn_mfma_f32_16x16x32_bf16(al, bh, acc[xg], 0, 0, 0);
        }
      }
    }
  }

  const int orow = y0 + rw;
#pragma unroll
  for (int reg = 0; reg < 4; ++reg) {
    const int co = co0 + cg * 16 + kg * 4 + reg;
    float* op = part + ((size_t)(b * 256 + co) * 48 + orow) * 48 + li;
#pragma unroll
    for (int xg = 0; xg < 3; ++xg) op[xg * 16] = acc[xg][reg];
  }
}

// ---------------------------------------------------------------------------
// Kernel 4c: y = selu(Cp0+Cp1+bias), transpose+split -> t1T hi/lo [b][s][c].
// grid (36 s-tiles, 4 co-tiles, B).
// ---------------------------------------------------------------------------
__global__ __launch_bounds__(256) void k_act_t(const float* __restrict__ p0,
                                               const float* __restrict__ p1,
                                               const float* __restrict__ bias,
                                               ushort_t* __restrict__ outTh,
                                               ushort_t* __restrict__ outTl) {
  __shared__ __align__(16) float t_s[64][65];
  const int tid = threadIdx.x;
  const int s0 = blockIdx.x * 64;
  const int co0 = blockIdx.y * 64;
  const int b  = blockIdx.z;

#pragma unroll
  for (int k = 0; k < 16; ++k) {
    int idx = tid + k * 256;
    int r = idx >> 6, c = idx & 63;
    size_t a = ((size_t)(b * 256 + co0 + r)) * S_TOT + s0 + c;
    float v = p0[a] + p1[a] + bias[co0 + r];
    v = 1.0507009873554805f * (v > 0.f ? v : 1.6732632423543772f * expm1f(v));
    t_s[r][c] = v;
  }
  __syncthreads();
#pragma unroll
  for (int k = 0; k < 16; ++k) {
    int idx = tid + k * 256;
    int p = idx >> 6, c = idx & 63;
    float v = t_s[c][p];
    ushort_t h = bf16_rn(v);
    float hf = __uint_as_float((unsigned)h << 16);
    ushort_t l = bf16_rn(v - hf);
    size_t o = ((size_t)b * S_TOT + s0 + p) * C_ + co0 + c;
    outTh[o] = h;
    outTl[o] = l;
  }
}

// ---------------------------------------------------------------------------
// Kernel 4d: out = Cp0 + Cp1 + bias (f32, no act)
// ---------------------------------------------------------------------------
__global__ __launch_bounds__(256) void k_act2(const float* __restrict__ p0,
                                              const float* __restrict__ p1,
                                              const float* __restrict__ bias,
                                              float* __restrict__ out) {
  size_t i4 = ((size_t)blockIdx.x * 256 + threadIdx.x) * 4;
  float4 a = *(const float4*)(p0 + i4);
  float4 b = *(const float4*)(p1 + i4);
  int co = (int)((i4 / (size_t)S_TOT) & 255);
  float bi = bias[co];
  float4 o;
  o.x = a.x + b.x + bi; o.y = a.y + b.y + bi;
  o.z = a.z + b.z + bi; o.w = a.w + b.w + bi;
  *(float4*)(out + i4) = o;
}

// ---------------------------------------------------------------------------
extern "C" void kernel_launch(void* const* d_in, const int* in_sizes, int n_in,
                              void* d_out, int out_size, void* d_ws, size_t ws_size,
                              hipStream_t stream) {
  const float* x   = (const float*)d_in[0];
  const float* ref = (const float*)d_in[1];
  const float* qW1 = (const float*)d_in[2];
  const float* qb1 = (const float*)d_in[3];
  const float* qW2 = (const float*)d_in[4];
  const float* qb2 = (const float*)d_in[5];
  const float* kW1 = (const float*)d_in[6];
  const float* kb1 = (const float*)d_in[7];
  const float* kW2 = (const float*)d_in[8];
  const float* kb2 = (const float*)d_in[9];
  const float* vW1 = (const float*)d_in[10];
  const float* vb1 = (const float*)d_in[11];
  const float* vW2 = (const float*)d_in[12];
  const float* vb2 = (const float*)d_in[13];
  const float* c1W = (const float*)d_in[14];
  const float* c1b = (const float*)d_in[15];
  const float* c2W = (const float*)d_in[16];
  const float* c2b = (const float*)d_in[17];

  float* out = (float*)d_out;
  float* probs = out + (size_t)B_ * C_ * S_TOT;       // [B][H][S][S]
  float* ws = (float*)d_ws;
  const size_t BSC = (size_t)B_ * S_TOT * C_;         // 1,179,648
  const size_t STATS = (size_t)JSPLIT * B_ * HEADS_ * S_TOT;
  const size_t WTSZ = (size_t)256 * 9 * 256;

  float* stz = ws;
  float* Pv0 = stz + STATS;
  float* Pv1 = Pv0 + BSC;
  float* Pv2 = Pv1 + BSC;
  float* endf = Pv2 + BSC;

  ushort_t* Qh  = (ushort_t*)endf;
  ushort_t* Ql  = Qh + BSC;
  ushort_t* Kh  = Ql + BSC;
  ushort_t* Kl  = Kh + BSC;
  ushort_t* VhT = Kl + BSC;
  ushort_t* VlT = VhT + BSC;
  ushort_t* cTh = VlT + BSC;
  ushort_t* cTl = cTh + BSC;
  ushort_t* t1h = cTl + BSC;
  ushort_t* t1l = t1h + BSC;
  ushort_t* Wh1 = t1l + BSC;
  ushort_t* Wl1 = Wh1 + WTSZ;
  ushort_t* Wh2 = Wl1 + WTSZ;
  ushort_t* Wl2 = Wh2 + WTSZ;
  ushort_t* Ubuf = Wl2 + WTSZ;   // ~170 MB

  // conv partials reuse Pv0/Pv1 (dead after pvred)
  float* Cp0 = Pv0;
  float* Cp1 = Pv1;

  dim3 blk(256);
  k_mlpf<<<dim3(72, B_, 4), blk, 0, stream>>>(x, ref,
                                              qW1, qb1, qW2, qb2,
                                              kW1, kb1, kW2, kb2,
                                              vW1, vb1, vW2, vb2,
                                              c1W, c2W,
                                              Qh, Ql, Kh, Kl, VhT, VlT,
                                              Wh1, Wl1, Wh2, Wl2);

  k_scores_mfma<<<dim3(36, JSPLIT, B_), blk, 0, stream>>>(Qh, Ql, Kh, Kl, Ubuf, stz);

  k_pv5<<<dim3(36, 8, 6), blk, 0, stream>>>(Ubuf, stz, VhT, VlT, probs, Pv0, Pv1, Pv2);
  k_pvred<<<dim3((int)(BSC / 1024)), blk, 0, stream>>>(Pv0, Pv1, Pv2, cTh, cTl);

  dim3 gconv(8, 24, 2 * B_);
  k_conv_mfma2<<<gconv, blk, 0, stream>>>(cTh, cTl, Wh1, Wl1, Cp0, Cp1);
  k_act_t<<<dim3(36, 4, B_), blk, 0, stream>>>(Cp0, Cp1, c1b, t1h, t1l);
  k_conv_mfma2<<<gconv, blk, 0, stream>>>(t1h, t1l, Wh2, Wl2, Cp0, Cp1);
  k_act2<<<dim3((int)(BSC / 1024)), blk, 0, stream>>>(Cp0, Cp1, c2b, out);
}